// Round 7
// baseline (108.248 us; speedup 1.0000x reference)
//
#include <hip/hip_runtime.h>

#define NCLS 20
#define IGNORE_INDEX (-1)
#define SCAN_BLOCKS 2048
#define PPB 2048            // pairs per scan block = 256 threads * 8
#define RBITS 18            // n = 262144 = 2^18 -> neighbor index fits 18 bits
#define PROC_THREADS 128    // ~103 surviving pairs per segment -> ~80% lane density

// ---- kernel A: scan pairs, compact survivors into per-block segments -------
// No global atomics: each block owns segs[block*PPB ..] and counts[block].
__global__ __launch_bounds__(256) void scan_kernel(
    const int* __restrict__ labels, const int* __restrict__ ref_idx,
    unsigned int* __restrict__ counts, unsigned int* __restrict__ segs,
    long long total_pairs) {
    __shared__ unsigned int s_buf[PPB];
    __shared__ int s_cnt;
    const int tid = threadIdx.x;
    if (tid == 0) s_cnt = 0;
    __syncthreads();

    const long long pair0 = (long long)blockIdx.x * PPB + (long long)tid * 8;
    if (pair0 + 8 <= total_pairs) {
        // 8 consecutive pairs belong to ONE point (8 | 16): single center-label load
        const int p = (int)(pair0 >> 4);
        const int li = labels[p];
        int4 ra = *(const int4*)(ref_idx + pair0);
        int4 rb = *(const int4*)(ref_idx + pair0 + 4);
        int rr[8] = {ra.x, ra.y, ra.z, ra.w, rb.x, rb.y, rb.z, rb.w};
        int nl[8];
#pragma unroll
        for (int j = 0; j < 8; ++j) nl[j] = labels[max(rr[j], 0)];  // 8 independent gathers
        if (li != IGNORE_INDEX) {
#pragma unroll
            for (int j = 0; j < 8; ++j) {
                if (rr[j] >= 0 && nl[j] == li) {       // nl==li>=0 implies nl valid
                    int slot = atomicAdd(&s_cnt, 1);   // LDS atomic: cheap
                    s_buf[slot] = ((unsigned int)(tid * 8 + j) << RBITS) |
                                  (unsigned int)rr[j];
                }
            }
        }
    }
    __syncthreads();
    const int c = s_cnt;
    unsigned int* seg = segs + (size_t)blockIdx.x * PPB;
    for (int i = tid; i < c; i += 256) seg[i] = s_buf[i];   // coalesced burst
    if (tid == 0) counts[blockIdx.x] = (unsigned int)c;     // plain store
}

// ---- kernel B: lane-dense pair processing, per-block partial sums ----------
__device__ __forceinline__ void softmax_row(const float* __restrict__ row, float* v) {
    const float4* r4 = (const float4*)row;   // 80B rows, 16B-aligned
#pragma unroll
    for (int q = 0; q < 5; ++q) {
        float4 t = r4[q];
        v[4 * q + 0] = t.x; v[4 * q + 1] = t.y;
        v[4 * q + 2] = t.z; v[4 * q + 3] = t.w;
    }
    float mx = v[0];
#pragma unroll
    for (int c = 1; c < NCLS; ++c) mx = fmaxf(mx, v[c]);
    float s = 0.f;
#pragma unroll
    for (int c = 0; c < NCLS; ++c) { v[c] = __expf(v[c] - mx); s += v[c]; }
    float inv = 1.0f / s;
#pragma unroll
    for (int c = 0; c < NCLS; ++c) v[c] *= inv;
}

__global__ __launch_bounds__(PROC_THREADS) void process_kernel(
    const float* __restrict__ logits,
    const unsigned int* __restrict__ counts, const unsigned int* __restrict__ segs,
    float* __restrict__ partials) {
    const int s = blockIdx.x;
    // CLAMP: counts may be poisoned (0xAA) in a rocprof isolated replay of this
    // kernel; without the clamp that loops ~11M times/block (R6's 40ms artifact).
    const unsigned int c = min(counts[s], (unsigned int)PPB);
    const unsigned int* seg = segs + (size_t)s * PPB;

    float fsum = 0.f;
    for (unsigned int i = threadIdx.x; i < c; i += PROC_THREADS) {
        unsigned int e = seg[i];
        unsigned int lid = e >> RBITS;                       // local pair id
        unsigned int r = e & ((1u << RBITS) - 1u);           // neighbor index
        unsigned int p = ((unsigned int)s * PPB + lid) >> 4; // center index
        float a[NCLS], b[NCLS];
        softmax_row(logits + (size_t)p * NCLS, a);
        softmax_row(logits + (size_t)r * NCLS, b);
        float d = 0.f;
#pragma unroll
        for (int k = 0; k < NCLS; ++k) {
            float dx = a[k] - b[k];
            d = fmaf(dx, dx, d);
        }
        fsum += d;
    }

    // block reduction (2 waves) -> plain store (no atomics)
#pragma unroll
    for (int off = 32; off > 0; off >>= 1) fsum += __shfl_down(fsum, off, 64);
    __shared__ float s_wsum[PROC_THREADS / 64];
    if ((threadIdx.x & 63) == 0) s_wsum[threadIdx.x >> 6] = fsum;
    __syncthreads();
    if (threadIdx.x == 0) {
        float t = 0.f;
#pragma unroll
        for (int w = 0; w < PROC_THREADS / 64; ++w) t += s_wsum[w];
        partials[s] = t;
    }
}

// ---- kernel C: single-block final reduction --------------------------------
__global__ __launch_bounds__(1024) void reduce_kernel(
    const float* __restrict__ partials, const unsigned int* __restrict__ counts,
    float* __restrict__ out, int m) {
    double dsum = 0.0;
    unsigned long long cnt = 0;
    for (int i = threadIdx.x; i < m; i += 1024) {
        dsum += (double)partials[i];
        cnt  += (unsigned long long)min(counts[i], (unsigned int)PPB);
    }
#pragma unroll
    for (int off = 32; off > 0; off >>= 1) {
        dsum += __shfl_down(dsum, off, 64);
        cnt  += __shfl_down(cnt,  off, 64);
    }
    __shared__ double s_sum[16];
    __shared__ unsigned long long s_cnt[16];
    const int wave = threadIdx.x >> 6;
    if ((threadIdx.x & 63) == 0) { s_sum[wave] = dsum; s_cnt[wave] = cnt; }
    __syncthreads();
    if (threadIdx.x == 0) {
        double ts = 0.0; unsigned long long tc = 0;
        for (int w = 0; w < 16; ++w) { ts += s_sum[w]; tc += s_cnt[w]; }
        if (tc < 1ull) tc = 1ull;
        out[0] = (float)(ts / (double)tc);     // LOSS_WEIGHT = 1.0
    }
}

extern "C" void kernel_launch(void* const* d_in, const int* in_sizes, int n_in,
                              void* d_out, int out_size, void* d_ws, size_t ws_size,
                              hipStream_t stream) {
    const float* seg_logits = (const float*)d_in[0];
    // d_in[1] = coord — unused (KNN indices are given)
    const int* labels  = (const int*)d_in[2];
    const int* ref_idx = (const int*)d_in[3];
    float* out = (float*)d_out;
    const int n = in_sizes[2];                       // 262144
    const long long total_pairs = (long long)n * 16; // 4,194,304

    // ws layout: counts[2048] | partials[2048] | segs[2048*2048]  (~16 MB)
    unsigned int* counts   = (unsigned int*)d_ws;
    float* partials        = (float*)((char*)d_ws + SCAN_BLOCKS * 4);
    unsigned int* segs     = (unsigned int*)((char*)d_ws + SCAN_BLOCKS * 8);

    scan_kernel<<<SCAN_BLOCKS, 256, 0, stream>>>(labels, ref_idx, counts, segs,
                                                 total_pairs);
    process_kernel<<<SCAN_BLOCKS, PROC_THREADS, 0, stream>>>(seg_logits, counts,
                                                             segs, partials);
    reduce_kernel<<<1, 1024, 0, stream>>>(partials, counts, out, SCAN_BLOCKS);
}

// Round 8
// 102.317 us; speedup vs baseline: 1.0580x; 1.0580x over previous
//
#include <hip/hip_runtime.h>

#define NCLS 20
#define IGNORE_INDEX (-1)
#define BLOCKS 2048
#define PPB 2048            // pairs per block = 256 threads * 8
#define RBITS 18            // n = 262144 = 2^18 -> neighbor index fits 18 bits

__device__ __forceinline__ void softmax_row(const float* __restrict__ row, float* v) {
    const float4* r4 = (const float4*)row;   // 80B rows, 16B-aligned
#pragma unroll
    for (int q = 0; q < 5; ++q) {
        float4 t = r4[q];
        v[4 * q + 0] = t.x; v[4 * q + 1] = t.y;
        v[4 * q + 2] = t.z; v[4 * q + 3] = t.w;
    }
    float mx = v[0];
#pragma unroll
    for (int c = 1; c < NCLS; ++c) mx = fmaxf(mx, v[c]);
    float s = 0.f;
#pragma unroll
    for (int c = 0; c < NCLS; ++c) { v[c] = __expf(v[c] - mx); s += v[c]; }
    float inv = 1.0f / s;
#pragma unroll
    for (int c = 0; c < NCLS; ++c) v[c] *= inv;
}

// Fused scan+process: 2048 blocks (32 waves/CU — R4's fusion failed at 1024
// blocks / 24.8% occupancy). Phase 1: 8 independent label gathers/thread,
// survivors compacted into LDS. Phase 2: lane-dense processing from LDS.
// Cross-block residency (≥8 blocks/CU) overlaps one block's phase 1 with
// another's phase 2. No global atomics, no segs round-trip.
__global__ __launch_bounds__(256) void fused_kernel(
    const float* __restrict__ logits, const int* __restrict__ labels,
    const int* __restrict__ ref_idx,
    unsigned int* __restrict__ counts, float* __restrict__ partials,
    long long total_pairs) {
    __shared__ unsigned int s_buf[PPB];   // 8 KB
    __shared__ int s_cnt;
    __shared__ float s_wsum[4];
    const int tid = threadIdx.x;
    if (tid == 0) s_cnt = 0;
    __syncthreads();

    // ---- phase 1: scan 8 pairs (half of one point's neighborhood) ----------
    const long long pair0 = (long long)blockIdx.x * PPB + (long long)tid * 8;
    if (pair0 + 8 <= total_pairs) {
        const int p = (int)(pair0 >> 4);       // 8 | 16: all 8 pairs share one center
        const int li = labels[p];
        int4 ra = *(const int4*)(ref_idx + pair0);
        int4 rb = *(const int4*)(ref_idx + pair0 + 4);
        int rr[8] = {ra.x, ra.y, ra.z, ra.w, rb.x, rb.y, rb.z, rb.w};
        int nl[8];
#pragma unroll
        for (int j = 0; j < 8; ++j) nl[j] = labels[max(rr[j], 0)];  // independent gathers
        if (li != IGNORE_INDEX) {
#pragma unroll
            for (int j = 0; j < 8; ++j) {
                if (rr[j] >= 0 && nl[j] == li) {     // nl==li>=0 implies nl valid
                    int slot = atomicAdd(&s_cnt, 1); // LDS atomic: cheap
                    s_buf[slot] = ((unsigned int)(tid * 8 + j) << RBITS) |
                                  (unsigned int)rr[j];
                }
            }
        }
    }
    __syncthreads();
    const int c = s_cnt;                        // <= PPB by construction

    // ---- phase 2: lane-dense pair processing straight from LDS -------------
    float fsum = 0.f;
    for (int i = tid; i < c; i += 256) {
        unsigned int e = s_buf[i];
        unsigned int lid = e >> RBITS;                        // local pair id [0,2048)
        unsigned int r = e & ((1u << RBITS) - 1u);            // neighbor index
        unsigned int p = (unsigned int)blockIdx.x * 128u + (lid >> 4);  // center
        float a[NCLS], b[NCLS];
        softmax_row(logits + (size_t)p * NCLS, a);
        softmax_row(logits + (size_t)r * NCLS, b);
        float d = 0.f;
#pragma unroll
        for (int k = 0; k < NCLS; ++k) {
            float dx = a[k] - b[k];
            d = fmaf(dx, dx, d);
        }
        fsum += d;
    }

    // ---- block reduction -> plain stores (no global atomics) ---------------
#pragma unroll
    for (int off = 32; off > 0; off >>= 1) fsum += __shfl_down(fsum, off, 64);
    if ((tid & 63) == 0) s_wsum[tid >> 6] = fsum;
    __syncthreads();
    if (tid == 0) {
        partials[blockIdx.x] = s_wsum[0] + s_wsum[1] + s_wsum[2] + s_wsum[3];
        counts[blockIdx.x] = (unsigned int)c;
    }
}

// ---- final single-block reduction ------------------------------------------
__global__ __launch_bounds__(1024) void reduce_kernel(
    const float* __restrict__ partials, const unsigned int* __restrict__ counts,
    float* __restrict__ out, int m) {
    double dsum = 0.0;
    unsigned long long cnt = 0;
    for (int i = threadIdx.x; i < m; i += 1024) {
        dsum += (double)partials[i];
        // clamp: counts may be 0xAA-poisoned in an isolated rocprof replay
        cnt  += (unsigned long long)min(counts[i], (unsigned int)PPB);
    }
#pragma unroll
    for (int off = 32; off > 0; off >>= 1) {
        dsum += __shfl_down(dsum, off, 64);
        cnt  += __shfl_down(cnt,  off, 64);
    }
    __shared__ double s_sum[16];
    __shared__ unsigned long long s_cnt[16];
    const int wave = threadIdx.x >> 6;
    if ((threadIdx.x & 63) == 0) { s_sum[wave] = dsum; s_cnt[wave] = cnt; }
    __syncthreads();
    if (threadIdx.x == 0) {
        double ts = 0.0; unsigned long long tc = 0;
        for (int w = 0; w < 16; ++w) { ts += s_sum[w]; tc += s_cnt[w]; }
        if (tc < 1ull) tc = 1ull;
        out[0] = (float)(ts / (double)tc);     // LOSS_WEIGHT = 1.0
    }
}

extern "C" void kernel_launch(void* const* d_in, const int* in_sizes, int n_in,
                              void* d_out, int out_size, void* d_ws, size_t ws_size,
                              hipStream_t stream) {
    const float* seg_logits = (const float*)d_in[0];
    // d_in[1] = coord — unused (KNN indices are given)
    const int* labels  = (const int*)d_in[2];
    const int* ref_idx = (const int*)d_in[3];
    float* out = (float*)d_out;
    const int n = in_sizes[2];                       // 262144
    const long long total_pairs = (long long)n * 16; // 4,194,304

    // ws layout: counts[2048] | partials[2048]  (16 KB)
    unsigned int* counts = (unsigned int*)d_ws;
    float* partials      = (float*)((char*)d_ws + BLOCKS * 4);

    fused_kernel<<<BLOCKS, 256, 0, stream>>>(seg_logits, labels, ref_idx,
                                             counts, partials, total_pairs);
    reduce_kernel<<<1, 1024, 0, stream>>>(partials, counts, out, BLOCKS);
}

// Round 9
// 101.594 us; speedup vs baseline: 1.0655x; 1.0071x over previous
//
#include <hip/hip_runtime.h>

#define NCLS 20
#define IGNORE_INDEX (-1)
#define TPB 128             // threads per block: 2-wave blocks, fine-grain scheduling
#define PAIRS_PER_THREAD 8
#define PPB (TPB * PAIRS_PER_THREAD)   // 1024 pairs per block
#define BLOCKS 4096                    // 4,194,304 / 1024
#define RBITS 18            // n = 262144 = 2^18 -> neighbor index fits 18 bits

__device__ __forceinline__ void softmax_row(const float* __restrict__ row, float* v) {
    const float4* r4 = (const float4*)row;   // 80B rows, 16B-aligned
#pragma unroll
    for (int q = 0; q < 5; ++q) {
        float4 t = r4[q];
        v[4 * q + 0] = t.x; v[4 * q + 1] = t.y;
        v[4 * q + 2] = t.z; v[4 * q + 3] = t.w;
    }
    float mx = v[0];
#pragma unroll
    for (int c = 1; c < NCLS; ++c) mx = fmaxf(mx, v[c]);
    float s = 0.f;
#pragma unroll
    for (int c = 0; c < NCLS; ++c) { v[c] = __expf(v[c] - mx); s += v[c]; }
    float inv = 1.0f / s;
#pragma unroll
    for (int c = 0; c < NCLS; ++c) v[c] *= inv;
}

// Fused scan+process at 4096 x 128: 2-wave barriers (vs 4-wave convoys at 256),
// 16 blocks/CU co-resident, 32 waves/CU. Phase 1: 8 independent label gathers
// per thread, survivors -> LDS. Phase 2: lane-dense processing from LDS.
// No global atomics (R5: same-address atomics cost ~11 ns each, serialized).
__global__ __launch_bounds__(TPB) void fused_kernel(
    const float* __restrict__ logits, const int* __restrict__ labels,
    const int* __restrict__ ref_idx,
    unsigned int* __restrict__ counts, float* __restrict__ partials,
    long long total_pairs) {
    __shared__ unsigned int s_buf[PPB];   // 4 KB
    __shared__ int s_cnt;
    __shared__ float s_wsum[TPB / 64];
    const int tid = threadIdx.x;
    if (tid == 0) s_cnt = 0;
    __syncthreads();

    // ---- phase 1: scan 8 pairs (half of one point's neighborhood) ----------
    const long long pair0 = (long long)blockIdx.x * PPB + (long long)tid * 8;
    if (pair0 + 8 <= total_pairs) {
        const int p = (int)(pair0 >> 4);       // 8 | 16: all 8 pairs share one center
        const int li = labels[p];
        int4 ra = *(const int4*)(ref_idx + pair0);
        int4 rb = *(const int4*)(ref_idx + pair0 + 4);
        int rr[8] = {ra.x, ra.y, ra.z, ra.w, rb.x, rb.y, rb.z, rb.w};
        int nl[8];
#pragma unroll
        for (int j = 0; j < 8; ++j) nl[j] = labels[max(rr[j], 0)];  // independent gathers
        if (li != IGNORE_INDEX) {
#pragma unroll
            for (int j = 0; j < 8; ++j) {
                if (rr[j] >= 0 && nl[j] == li) {     // nl==li>=0 implies nl valid
                    int slot = atomicAdd(&s_cnt, 1); // LDS atomic: cheap
                    s_buf[slot] = ((unsigned int)(tid * 8 + j) << RBITS) |
                                  (unsigned int)rr[j];
                }
            }
        }
    }
    __syncthreads();
    const int c = s_cnt;                        // <= PPB by construction

    // ---- phase 2: lane-dense pair processing straight from LDS -------------
    float fsum = 0.f;
    for (int i = tid; i < c; i += TPB) {
        unsigned int e = s_buf[i];
        unsigned int lid = e >> RBITS;                        // local pair id [0,1024)
        unsigned int r = e & ((1u << RBITS) - 1u);            // neighbor index
        unsigned int p = (unsigned int)blockIdx.x * (PPB / 16) + (lid >> 4);
        float a[NCLS], b[NCLS];
        softmax_row(logits + (size_t)p * NCLS, a);
        softmax_row(logits + (size_t)r * NCLS, b);
        float d = 0.f;
#pragma unroll
        for (int k = 0; k < NCLS; ++k) {
            float dx = a[k] - b[k];
            d = fmaf(dx, dx, d);
        }
        fsum += d;
    }

    // ---- block reduction -> plain stores (no global atomics) ---------------
#pragma unroll
    for (int off = 32; off > 0; off >>= 1) fsum += __shfl_down(fsum, off, 64);
    if ((tid & 63) == 0) s_wsum[tid >> 6] = fsum;
    __syncthreads();
    if (tid == 0) {
        float t = 0.f;
#pragma unroll
        for (int w = 0; w < TPB / 64; ++w) t += s_wsum[w];
        partials[blockIdx.x] = t;
        counts[blockIdx.x] = (unsigned int)c;
    }
}

// ---- final single-block reduction ------------------------------------------
__global__ __launch_bounds__(1024) void reduce_kernel(
    const float* __restrict__ partials, const unsigned int* __restrict__ counts,
    float* __restrict__ out, int m) {
    double dsum = 0.0;
    unsigned long long cnt = 0;
    for (int i = threadIdx.x; i < m; i += 1024) {
        dsum += (double)partials[i];
        // clamp: counts may be 0xAA-poisoned in an isolated rocprof replay
        cnt  += (unsigned long long)min(counts[i], (unsigned int)PPB);
    }
#pragma unroll
    for (int off = 32; off > 0; off >>= 1) {
        dsum += __shfl_down(dsum, off, 64);
        cnt  += __shfl_down(cnt,  off, 64);
    }
    __shared__ double s_sum[16];
    __shared__ unsigned long long s_cnt[16];
    const int wave = threadIdx.x >> 6;
    if ((threadIdx.x & 63) == 0) { s_sum[wave] = dsum; s_cnt[wave] = cnt; }
    __syncthreads();
    if (threadIdx.x == 0) {
        double ts = 0.0; unsigned long long tc = 0;
        for (int w = 0; w < 16; ++w) { ts += s_sum[w]; tc += s_cnt[w]; }
        if (tc < 1ull) tc = 1ull;
        out[0] = (float)(ts / (double)tc);     // LOSS_WEIGHT = 1.0
    }
}

extern "C" void kernel_launch(void* const* d_in, const int* in_sizes, int n_in,
                              void* d_out, int out_size, void* d_ws, size_t ws_size,
                              hipStream_t stream) {
    const float* seg_logits = (const float*)d_in[0];
    // d_in[1] = coord — unused (KNN indices are given)
    const int* labels  = (const int*)d_in[2];
    const int* ref_idx = (const int*)d_in[3];
    float* out = (float*)d_out;
    const int n = in_sizes[2];                       // 262144
    const long long total_pairs = (long long)n * 16; // 4,194,304

    // ws layout: counts[4096] | partials[4096]  (32 KB)
    unsigned int* counts = (unsigned int*)d_ws;
    float* partials      = (float*)((char*)d_ws + BLOCKS * 4);

    fused_kernel<<<BLOCKS, TPB, 0, stream>>>(seg_logits, labels, ref_idx,
                                             counts, partials, total_pairs);
    reduce_kernel<<<1, 1024, 0, stream>>>(partials, counts, out, BLOCKS);
}